// Round 5
// baseline (256.815 us; speedup 1.0000x reference)
//
#include <hip/hip_runtime.h>
#include <hip/hip_bf16.h>
#include <hip/hip_fp8.h>
#include <stdint.h>

// Shapes: b=2, n=5, k=5, q=75, t=196, c=384, s=k*t=980 (padded to 1024/class)
// M per b = 75*196 = 14700 (padded to 14720 = 115 tiles of 128)
// Outputs: logits [2,75,5] then cls_logits [2,75,5]
// Sim branch: fp8-e4m3 MX-scaled MFMA (scales=1.0); cls branch exact fp32.
// gemm: 128x64 tile, FULL K=384 resident in LDS (3 planes of the round-4 layout),
// straight-line compute, 2 barriers + 1 vmcnt drain per block.

typedef __attribute__((ext_vector_type(8))) int int8v;      // f8f6f4 A/B operand (32 fp8)
typedef __attribute__((ext_vector_type(4))) float f32x4;    // MFMA C/D frag

__device__ __forceinline__ void load_lds16(const void* g, void* l) {
    __builtin_amdgcn_global_load_lds(
        (const __attribute__((address_space(1))) unsigned int*)(uintptr_t)g,
        (__attribute__((address_space(3))) unsigned int*)(uintptr_t)l,
        16, 0, 0);
}

__device__ __forceinline__ unsigned enc_f(float f) {
    unsigned b = __float_as_uint(f);
    return (b & 0x80000000u) ? ~b : (b | 0x80000000u);
}
__device__ __forceinline__ float dec_f(unsigned u) {
    unsigned b = (u & 0x80000000u) ? (u & 0x7FFFFFFFu) : ~u;
    return __uint_as_float(b);
}

__device__ __forceinline__ unsigned pack4_fp8(float a, float b, float c, float d) {
    int r = __builtin_amdgcn_cvt_pk_fp8_f32(a, b, 0, false);   // bytes 0,1
    r = __builtin_amdgcn_cvt_pk_fp8_f32(c, d, r, true);        // bytes 2,3
    return (unsigned)r;
}

// L2-normalize a 384-float row, emit 384 fp8 bytes (96 uint stores).
// Lane l loads float4 #l; lanes 0..31 also load float4 #(64+l).
__device__ __forceinline__ void norm_row_fp8(const float* __restrict__ row,
                                             unsigned* __restrict__ o32, int lane) {
    const float4* rf4 = (const float4*)row;
    const float4 v0 = rf4[lane];
    float4 v1 = make_float4(0.f, 0.f, 0.f, 0.f);
    if (lane < 32) v1 = rf4[64 + lane];
    float ss = v0.x * v0.x + v0.y * v0.y + v0.z * v0.z + v0.w * v0.w
             + v1.x * v1.x + v1.y * v1.y + v1.z * v1.z + v1.w * v1.w;
#pragma unroll
    for (int off = 1; off < 64; off <<= 1) ss += __shfl_xor(ss, off, 64);
    const float sc = 1.0f / fmaxf(sqrtf(ss), 1e-8f);
    o32[lane] = pack4_fp8(v0.x * sc, v0.y * sc, v0.z * sc, v0.w * sc);
    if (lane < 32) o32[64 + lane] = pack4_fp8(v1.x * sc, v1.y * sc, v1.z * sc, v1.w * sc);
}

// ---------------- fused prep: norm_q | norm_s(padded) | proto | init_P ----------------
__global__ void prep_kernel(const float* __restrict__ feat_query,
                            const float* __restrict__ feat_shot,
                            const float* __restrict__ x_shot,
                            unsigned* __restrict__ fqn,
                            unsigned* __restrict__ fsnp,
                            float* __restrict__ proto,
                            unsigned* __restrict__ P) {
    const int blk  = blockIdx.x;
    const int tid  = threadIdx.x;
    const int lane = tid & 63;
    const int wv   = tid >> 6;

    if (blk < 7350) {                       // ---- query token norm -> fp8 ----
        const int gw = blk * 4 + wv;        // 0..29399
        if (gw >= 29400) return;
        norm_row_fp8(feat_query + (size_t)gw * 384, fqn + (size_t)gw * 96, lane);
    } else if (blk < 9910) {                // ---- shot token norm -> fp8 padded layout ----
        const int gw = (blk - 7350) * 4 + wv;   // 0..10239
        if (gw >= 10240) return;
        const int bn = gw >> 10;
        const int s  = gw & 1023;
        unsigned* o32 = fsnp + (size_t)gw * 96;
        if (s >= 980) {
            o32[lane] = 0u;
            if (lane < 32) o32[64 + lane] = 0u;
            return;
        }
        norm_row_fp8(feat_shot + ((size_t)bn * 980 + s) * 384, o32, lane);
    } else if (blk < 9913) {                // ---- proto = l2norm(mean_k x_shot), fp32 ----
        const int gw = (blk - 9910) * 4 + wv;
        if (gw >= 10) return;
        const float* base = x_shot + (size_t)gw * 5 * 384;
        float v[6];
        float ss = 0.f;
#pragma unroll
        for (int j = 0; j < 6; ++j) {
            float s = 0.f;
#pragma unroll
            for (int kk = 0; kk < 5; ++kk) s += base[kk * 384 + lane + 64 * j];
            s *= 0.2f;
            v[j] = s;
            ss += s * s;
        }
#pragma unroll
        for (int off = 1; off < 64; off <<= 1) ss += __shfl_xor(ss, off, 64);
        const float scale = 1.0f / fmaxf(sqrtf(ss), 1e-12f);
#pragma unroll
        for (int j = 0; j < 6; ++j) proto[(size_t)gw * 384 + lane + 64 * j] = v[j] * scale;
    } else {                                // ---- init P to encoded -inf (0) ----
        const int i = (blk - 9913) * 256 + tid;
        if (i < 147000) P[i] = 0u;
    }
}

// ---------------- batched fp8 GEMM + row-max: 128x64 tile, FULL K in LDS ----------------
// 3 K-planes per matrix, each plane = round-4 layout: rows of 128 B = 8 granules of 16 B,
// granule slot g holds source granule g ^ (r&7). Frag reads at ((2hi+c)^(l15&7)) granules.
// MFMA: mfma_scale_f32_16x16x128_f8f6f4, scales = 0x7F (1.0) => plain fp8 matmul.
// Waves: (wv&1) = m-half (64 rows), (wv>>1) = s-half (32 cols); wave tile 64x32 = 4x2 frags.
__global__ __launch_bounds__(256, 2) void gemm_kernel(const uint8_t* __restrict__ fqn,
                                                      const uint8_t* __restrict__ fsnp,
                                                      unsigned* __restrict__ P) {
    __shared__ __align__(16) uint8_t Atile[3 * 16384];   // 48 KB: [plane][128 rows][128 B]
    __shared__ __align__(16) uint8_t Btile[3 * 8192];    // 24 KB: [plane][ 64 rows][128 B]
    __shared__ float red[2][128];                        //  1 KB

    const int bid = blockIdx.x;
    const int b   = bid / 9200;
    const int r   = bid % 9200;
    const int mt  = r / 80;
    const int st  = r % 80;
    const int m0  = mt * 128;          // row in [0,14720)
    const int s0  = st * 64;           // col in padded [0,5120)
    const int cls = s0 >> 10;          // class n
    const int s_loc = s0 & 1023;       // class-local col base

    const uint8_t* Ag = fqn  + (size_t)b * 14700 * 384;
    const uint8_t* Bg = fsnp + ((size_t)b * 5120 + s0) * 384;

    const int tid  = threadIdx.x;
    const int lane = tid & 63;
    const int wv   = tid >> 6;
    const int l15  = lane & 15;
    const int hi   = lane >> 4;
    const int m0w  = (wv & 1) * 64;    // wave m-offset
    const int n0w  = (wv >> 1) * 32;   // wave s-offset
    const int swz  = l15 & 7;

    // staging: row = i*32 + (tid>>3); LDS slot granule = tid&7;
    // source granule = (tid&7) ^ (row&7)  (i*32 is 0 mod 8).
    const int g_row   = tid >> 3;                        // 0..31
    const int src_off = ((tid & 7) ^ (g_row & 7)) * 16;  // source byte offset in 128B chunk

    // ---- stage everything (18 load_lds per thread), one drain ----
#pragma unroll
    for (int p = 0; p < 3; ++p) {
#pragma unroll
        for (int i = 0; i < 4; ++i) {
            const int row = i * 32 + g_row;
            if (m0 + row < 14700)
                load_lds16(Ag + (size_t)(m0 + row) * 384 + p * 128 + src_off,
                           &Atile[p * 16384 + (i * 256 + wv * 64) * 16]);
        }
#pragma unroll
        for (int i = 0; i < 2; ++i) {
            const int row = i * 32 + g_row;
            load_lds16(Bg + (size_t)row * 384 + p * 128 + src_off,
                       &Btile[p * 8192 + (i * 256 + wv * 64) * 16]);
        }
    }
    __syncthreads();

    // ---- straight-line compute: 3 ksteps x (4 A-frags, 2 B-frags, 8 MFMA) ----
    f32x4 acc[4][2];
#pragma unroll
    for (int mi = 0; mi < 4; ++mi)
#pragma unroll
        for (int ni = 0; ni < 2; ++ni) acc[mi][ni] = (f32x4){0.f, 0.f, 0.f, 0.f};

    const int c0 = ((2 * hi + 0) ^ swz) * 16;
    const int c1 = ((2 * hi + 1) ^ swz) * 16;

#pragma unroll
    for (int ks = 0; ks < 3; ++ks) {
        int8v af[4], bf[2];
#pragma unroll
        for (int mi = 0; mi < 4; ++mi) {
            const uint8_t* base = &Atile[ks * 16384 + (m0w + mi * 16 + l15) * 128];
            const uint4 x = *(const uint4*)(base + c0);
            const uint4 y = *(const uint4*)(base + c1);
            af[mi] = (int8v){(int)x.x, (int)x.y, (int)x.z, (int)x.w,
                             (int)y.x, (int)y.y, (int)y.z, (int)y.w};
        }
#pragma unroll
        for (int ni = 0; ni < 2; ++ni) {
            const uint8_t* base = &Btile[ks * 8192 + (n0w + ni * 16 + l15) * 128];
            const uint4 x = *(const uint4*)(base + c0);
            const uint4 y = *(const uint4*)(base + c1);
            bf[ni] = (int8v){(int)x.x, (int)x.y, (int)x.z, (int)x.w,
                             (int)y.x, (int)y.y, (int)y.z, (int)y.w};
        }
#pragma unroll
        for (int mi = 0; mi < 4; ++mi)
#pragma unroll
            for (int ni = 0; ni < 2; ++ni)
                acc[mi][ni] = __builtin_amdgcn_mfma_scale_f32_16x16x128_f8f6f4(
                    af[mi], bf[ni], acc[mi][ni],
                    0, 0,                    // cbsz=fp8(e4m3), blgp=fp8(e4m3)
                    0, 0x7F7F7F7F,           // scale_a = 1.0
                    0, 0x7F7F7F7F);          // scale_b = 1.0
    }

    // ---- epilogue: per-row max over this block's 64 cols (masked at class boundary) ----
    float rmax[4][4];
#pragma unroll
    for (int mi = 0; mi < 4; ++mi)
#pragma unroll
        for (int i = 0; i < 4; ++i) rmax[mi][i] = -3.0e38f;

    const int scol = s_loc + n0w + l15;   // lane's class-local col (+ ni*16)
#pragma unroll
    for (int ni = 0; ni < 2; ++ni) {
        if (scol + ni * 16 < 980) {
#pragma unroll
            for (int mi = 0; mi < 4; ++mi)
#pragma unroll
                for (int i = 0; i < 4; ++i)
                    rmax[mi][i] = fmaxf(rmax[mi][i], acc[mi][ni][i]);
        }
    }
#pragma unroll
    for (int mi = 0; mi < 4; ++mi)
#pragma unroll
        for (int i = 0; i < 4; ++i) {
            float v = rmax[mi][i];
#pragma unroll
            for (int off = 1; off < 16; off <<= 1) v = fmaxf(v, __shfl_xor(v, off, 64));
            rmax[mi][i] = v;
        }
    if (l15 == 0) {
#pragma unroll
        for (int mi = 0; mi < 4; ++mi)
#pragma unroll
            for (int i = 0; i < 4; ++i)
                red[wv >> 1][m0w + mi * 16 + hi * 4 + i] = rmax[mi][i];
    }
    __syncthreads();
    if (tid < 128) {
        const int grow = m0 + tid;
        if (grow < 14700) {
            const float v = fmaxf(red[0][tid], red[1][tid]);
            atomicMax(&P[(size_t)(b * 5 + cls) * 14700 + grow], enc_f(v));
        }
    }
}

// ---------------- fused final: logits (mean over t of row maxima) | cls_logits ----------------
__global__ void final_kernel(const unsigned* __restrict__ P,
                             const float* __restrict__ xq,
                             const float* __restrict__ proto,
                             float* __restrict__ out) {
    const int blk  = blockIdx.x;
    const int tid  = threadIdx.x;
    const int lane = tid & 63;
    const int wv   = tid >> 6;

    if (blk < 188) {                        // ---- logits ----
        const int gw = blk * 4 + wv;        // (b*75+q)*5+n
        if (gw >= 750) return;
        const int n  = gw % 5;
        const int bq = gw / 5;
        const int b  = bq / 75;
        const int q  = bq % 75;
        const unsigned* row = P + (size_t)(b * 5 + n) * 14700 + q * 196;
        float s = 0.f;
        for (int t = lane; t < 196; t += 64) s += dec_f(row[t]);
#pragma unroll
        for (int off = 1; off < 64; off <<= 1) s += __shfl_xor(s, off, 64);
        if (lane == 0) out[gw] = s * (1.0f / 196.0f);
    } else {                                // ---- cls_logits ----
        const int gw = (blk - 188) * 4 + wv;   // b*75+q
        if (gw >= 150) return;
        const float* row = xq + (size_t)gw * 384;
        float u[6];
        float ss = 0.f;
#pragma unroll
        for (int j = 0; j < 6; ++j) { u[j] = row[lane + 64 * j]; ss += u[j] * u[j]; }
#pragma unroll
        for (int off = 1; off < 64; off <<= 1) ss += __shfl_xor(ss, off, 64);
        const float scale = 1.0f / fmaxf(sqrtf(ss), 1e-12f);
#pragma unroll
        for (int j = 0; j < 6; ++j) u[j] *= scale;
        const int b = gw / 75;
        for (int n = 0; n < 5; ++n) {
            const float* p = proto + (size_t)(b * 5 + n) * 384;
            float d = 0.f;
#pragma unroll
            for (int j = 0; j < 6; ++j) d += u[j] * p[lane + 64 * j];
#pragma unroll
            for (int off = 1; off < 64; off <<= 1) d += __shfl_xor(d, off, 64);
            if (lane == 0) out[750 + gw * 5 + n] = 10.0f * d;
        }
    }
}

extern "C" void kernel_launch(void* const* d_in, const int* in_sizes, int n_in,
                              void* d_out, int out_size, void* d_ws, size_t ws_size,
                              hipStream_t stream) {
    const float* feat_shot  = (const float*)d_in[0];  // [2,5,5,196,384]
    const float* feat_query = (const float*)d_in[1];  // [2,75,196,384]
    const float* x_shot     = (const float*)d_in[2];  // [2,5,5,384]
    const float* x_query    = (const float*)d_in[3];  // [2,75,384]
    float* out = (float*)d_out;
    char* ws = (char*)d_ws;

    // ws layout (15.8 MiB total)
    uint8_t*  fqn   = (uint8_t*)ws;                     // 29400*384  = 11,289,600 B (fp8)
    uint8_t*  fsnp  = (uint8_t*)(ws + 11289600);        // 10240*384  =  3,932,160 B (fp8)
    float*    proto = (float*)(ws + 15221760);          //      3,840 f32
    unsigned* P     = (unsigned*)(ws + 15237120);       //    147,000 u32

    prep_kernel<<<10488, 256, 0, stream>>>(feat_query, feat_shot, x_shot,
                                           (unsigned*)fqn, (unsigned*)fsnp, proto, P);
    gemm_kernel<<<2 * 115 * 80, 256, 0, stream>>>(fqn, fsnp, P);
    final_kernel<<<226, 256, 0, stream>>>(P, x_query, proto, out);
}

// Round 6
// 220.887 us; speedup vs baseline: 1.1627x; 1.1627x over previous
//
#include <hip/hip_runtime.h>
#include <hip/hip_bf16.h>
#include <hip/hip_fp8.h>
#include <stdint.h>

// Shapes: b=2, n=5, k=5, q=75, t=196, c=384, s=k*t=980 (padded to 1024/class)
// M per b = 75*196 = 14700 (padded to 14720 = 115 tiles of 128)
// Outputs: logits [2,75,5] then cls_logits [2,75,5]
// Sim branch: fp8-e4m3 MX-scaled MFMA (scales=1.0); cls branch exact fp32.
// gemm: NO LDS, NO barriers. A fragments register-resident (K=384 fp8 = 96 B/lane),
// B streamed global->VGPR in 16-col groups, MFMA<->load interleaved (AITER-style).

typedef __attribute__((ext_vector_type(8))) int int8v;      // f8f6f4 A/B operand (32 fp8)
typedef __attribute__((ext_vector_type(4))) float f32x4;    // MFMA C/D frag

__device__ __forceinline__ unsigned enc_f(float f) {
    unsigned b = __float_as_uint(f);
    return (b & 0x80000000u) ? ~b : (b | 0x80000000u);
}
__device__ __forceinline__ float dec_f(unsigned u) {
    unsigned b = (u & 0x80000000u) ? (u & 0x7FFFFFFFu) : ~u;
    return __uint_as_float(b);
}

__device__ __forceinline__ unsigned pack4_fp8(float a, float b, float c, float d) {
    int r = __builtin_amdgcn_cvt_pk_fp8_f32(a, b, 0, false);   // bytes 0,1
    r = __builtin_amdgcn_cvt_pk_fp8_f32(c, d, r, true);        // bytes 2,3
    return (unsigned)r;
}

// L2-normalize a 384-float row, emit 384 fp8 bytes (96 uint stores).
__device__ __forceinline__ void norm_row_fp8(const float* __restrict__ row,
                                             unsigned* __restrict__ o32, int lane) {
    const float4* rf4 = (const float4*)row;
    const float4 v0 = rf4[lane];
    float4 v1 = make_float4(0.f, 0.f, 0.f, 0.f);
    if (lane < 32) v1 = rf4[64 + lane];
    float ss = v0.x * v0.x + v0.y * v0.y + v0.z * v0.z + v0.w * v0.w
             + v1.x * v1.x + v1.y * v1.y + v1.z * v1.z + v1.w * v1.w;
#pragma unroll
    for (int off = 1; off < 64; off <<= 1) ss += __shfl_xor(ss, off, 64);
    const float sc = 1.0f / fmaxf(sqrtf(ss), 1e-8f);
    o32[lane] = pack4_fp8(v0.x * sc, v0.y * sc, v0.z * sc, v0.w * sc);
    if (lane < 32) o32[64 + lane] = pack4_fp8(v1.x * sc, v1.y * sc, v1.z * sc, v1.w * sc);
}

// ---------------- fused prep: norm_q | norm_s(padded) | proto | init_P ----------------
__global__ void prep_kernel(const float* __restrict__ feat_query,
                            const float* __restrict__ feat_shot,
                            const float* __restrict__ x_shot,
                            unsigned* __restrict__ fqn,
                            unsigned* __restrict__ fsnp,
                            float* __restrict__ proto,
                            unsigned* __restrict__ P) {
    const int blk  = blockIdx.x;
    const int tid  = threadIdx.x;
    const int lane = tid & 63;
    const int wv   = tid >> 6;

    if (blk < 7350) {                       // ---- query token norm -> fp8 ----
        const int gw = blk * 4 + wv;        // 0..29399
        if (gw >= 29400) return;
        norm_row_fp8(feat_query + (size_t)gw * 384, fqn + (size_t)gw * 96, lane);
    } else if (blk < 9910) {                // ---- shot token norm -> fp8 padded layout ----
        const int gw = (blk - 7350) * 4 + wv;   // 0..10239
        if (gw >= 10240) return;
        const int bn = gw >> 10;
        const int s  = gw & 1023;
        unsigned* o32 = fsnp + (size_t)gw * 96;
        if (s >= 980) {
            o32[lane] = 0u;
            if (lane < 32) o32[64 + lane] = 0u;
            return;
        }
        norm_row_fp8(feat_shot + ((size_t)bn * 980 + s) * 384, o32, lane);
    } else if (blk < 9913) {                // ---- proto = l2norm(mean_k x_shot), fp32 ----
        const int gw = (blk - 9910) * 4 + wv;
        if (gw >= 10) return;
        const float* base = x_shot + (size_t)gw * 5 * 384;
        float v[6];
        float ss = 0.f;
#pragma unroll
        for (int j = 0; j < 6; ++j) {
            float s = 0.f;
#pragma unroll
            for (int kk = 0; kk < 5; ++kk) s += base[kk * 384 + lane + 64 * j];
            s *= 0.2f;
            v[j] = s;
            ss += s * s;
        }
#pragma unroll
        for (int off = 1; off < 64; off <<= 1) ss += __shfl_xor(ss, off, 64);
        const float scale = 1.0f / fmaxf(sqrtf(ss), 1e-12f);
#pragma unroll
        for (int j = 0; j < 6; ++j) proto[(size_t)gw * 384 + lane + 64 * j] = v[j] * scale;
    } else {                                // ---- init P to encoded -inf (0) ----
        const int i = (blk - 9913) * 256 + tid;
        if (i < 147000) P[i] = 0u;
    }
}

// ---------------- barrier-free fp8 GEMM + row-max ----------------
// grid = 2b x 115mt x 5cls blocks, 256 threads = 4 waves = (2 m-halves) x (2 s-halves).
// Per wave: 64 m-rows (A frags in registers: 4mi x 3ks x 32B/lane), streams its class's
// 512 padded cols in 32 groups of 16. Per group: 6 global dwordx4 (B) + 12 MFMA.
// Operand layout (verified rounds 4/5): lane l15 = row/col, k-bytes = hi*32 + ks*128.
// C/D: col = lane&15, row = (lane>>4)*4 + reg. Epilogue: xor-reduce over l15, atomicMax.
__global__ __launch_bounds__(256, 2) void gemm_kernel(const uint8_t* __restrict__ fqn,
                                                      const uint8_t* __restrict__ fsnp,
                                                      unsigned* __restrict__ P) {
    const int bid = blockIdx.x;
    const int b   = bid / 575;
    const int r   = bid % 575;
    const int mt  = r / 5;
    const int cls = r % 5;
    const int m0  = mt * 128;

    const int tid  = threadIdx.x;
    const int lane = tid & 63;
    const int wv   = tid >> 6;
    const int wm   = wv & 1;          // m-half (64 rows)
    const int ws   = wv >> 1;         // s-half (16-col offset within each 32-col step)
    const int l15  = lane & 15;
    const int hi   = lane >> 4;

    const uint8_t* Ag = fqn  + (size_t)b * 14700 * 384;
    const uint8_t* Bg = fsnp + (size_t)(b * 5 + cls) * 1024 * 384;

    // ---- A fragments -> registers (one-time, ~96 VGPR) ----
    int8v A[4][3];
#pragma unroll
    for (int mi = 0; mi < 4; ++mi) {
        int row = m0 + wm * 64 + mi * 16 + l15;
        row = row < 14700 ? row : 14699;           // clamp; dead rows discarded at epilogue
        const uint8_t* pa = Ag + (size_t)row * 384 + hi * 32;
#pragma unroll
        for (int ks = 0; ks < 3; ++ks) {
            const uint4 x = *(const uint4*)(pa + ks * 128);
            const uint4 y = *(const uint4*)(pa + ks * 128 + 16);
            A[mi][ks] = (int8v){(int)x.x, (int)x.y, (int)x.z, (int)x.w,
                                (int)y.x, (int)y.y, (int)y.z, (int)y.w};
        }
    }

    float rmax[4][4];
#pragma unroll
    for (int mi = 0; mi < 4; ++mi)
#pragma unroll
        for (int i = 0; i < 4; ++i) rmax[mi][i] = -3.0e38f;

    // lane's B pointer for group 0: col = ws*16 + l15, k-offset hi*32
    const uint8_t* pb0 = Bg + (size_t)(ws * 16 + l15) * 384 + hi * 32;

    // ---- stream 32 groups of 16 cols, 1-deep manual pipeline ----
    int8v Bcur[3];
#pragma unroll
    for (int ks = 0; ks < 3; ++ks) {
        const uint4 x = *(const uint4*)(pb0 + ks * 128);
        const uint4 y = *(const uint4*)(pb0 + ks * 128 + 16);
        Bcur[ks] = (int8v){(int)x.x, (int)x.y, (int)x.z, (int)x.w,
                           (int)y.x, (int)y.y, (int)y.z, (int)y.w};
    }

#pragma unroll 2
    for (int it = 0; it < 32; ++it) {
        int8v Bnxt[3];
        if (it + 1 < 32) {
            const uint8_t* pb = pb0 + (size_t)(it + 1) * 32 * 384;
#pragma unroll
            for (int ks = 0; ks < 3; ++ks) {
                const uint4 x = *(const uint4*)(pb + ks * 128);
                const uint4 y = *(const uint4*)(pb + ks * 128 + 16);
                Bnxt[ks] = (int8v){(int)x.x, (int)x.y, (int)x.z, (int)x.w,
                                   (int)y.x, (int)y.y, (int)y.z, (int)y.w};
            }
        }

        f32x4 acc[4];
#pragma unroll
        for (int mi = 0; mi < 4; ++mi) acc[mi] = (f32x4){0.f, 0.f, 0.f, 0.f};
#pragma unroll
        for (int ks = 0; ks < 3; ++ks)
#pragma unroll
            for (int mi = 0; mi < 4; ++mi)
                acc[mi] = __builtin_amdgcn_mfma_scale_f32_16x16x128_f8f6f4(
                    A[mi][ks], Bcur[ks], acc[mi],
                    0, 0,                    // cbsz=fp8(e4m3), blgp=fp8(e4m3)
                    0, 0x7F7F7F7F,           // scale_a = 1.0
                    0, 0x7F7F7F7F);          // scale_b = 1.0

        const int colLocal = it * 32 + ws * 16 + l15;
        if (colLocal < 980) {
#pragma unroll
            for (int mi = 0; mi < 4; ++mi)
#pragma unroll
                for (int i = 0; i < 4; ++i)
                    rmax[mi][i] = fmaxf(rmax[mi][i], acc[mi][i]);
        }
#pragma unroll
        for (int ks = 0; ks < 3; ++ks) Bcur[ks] = Bnxt[ks];
    }

    // ---- epilogue: max over the 16 col-lanes, then device-scope atomicMax ----
#pragma unroll
    for (int mi = 0; mi < 4; ++mi)
#pragma unroll
        for (int i = 0; i < 4; ++i) {
            float v = rmax[mi][i];
#pragma unroll
            for (int off = 1; off < 16; off <<= 1) v = fmaxf(v, __shfl_xor(v, off, 64));
            if (l15 == 0) {
                const int row = m0 + wm * 64 + mi * 16 + hi * 4 + i;
                if (row < 14700)
                    atomicMax(&P[(size_t)(b * 5 + cls) * 14700 + row], enc_f(v));
            }
        }
}

// ---------------- fused final: logits (mean over t of row maxima) | cls_logits ----------------
__global__ void final_kernel(const unsigned* __restrict__ P,
                             const float* __restrict__ xq,
                             const float* __restrict__ proto,
                             float* __restrict__ out) {
    const int blk  = blockIdx.x;
    const int tid  = threadIdx.x;
    const int lane = tid & 63;
    const int wv   = tid >> 6;

    if (blk < 188) {                        // ---- logits ----
        const int gw = blk * 4 + wv;        // (b*75+q)*5+n
        if (gw >= 750) return;
        const int n  = gw % 5;
        const int bq = gw / 5;
        const int b  = bq / 75;
        const int q  = bq % 75;
        const unsigned* row = P + (size_t)(b * 5 + n) * 14700 + q * 196;
        float s = 0.f;
        for (int t = lane; t < 196; t += 64) s += dec_f(row[t]);
#pragma unroll
        for (int off = 1; off < 64; off <<= 1) s += __shfl_xor(s, off, 64);
        if (lane == 0) out[gw] = s * (1.0f / 196.0f);
    } else {                                // ---- cls_logits ----
        const int gw = (blk - 188) * 4 + wv;   // b*75+q
        if (gw >= 150) return;
        const float* row = xq + (size_t)gw * 384;
        float u[6];
        float ss = 0.f;
#pragma unroll
        for (int j = 0; j < 6; ++j) { u[j] = row[lane + 64 * j]; ss += u[j] * u[j]; }
#pragma unroll
        for (int off = 1; off < 64; off <<= 1) ss += __shfl_xor(ss, off, 64);
        const float scale = 1.0f / fmaxf(sqrtf(ss), 1e-12f);
#pragma unroll
        for (int j = 0; j < 6; ++j) u[j] *= scale;
        const int b = gw / 75;
        for (int n = 0; n < 5; ++n) {
            const float* p = proto + (size_t)(b * 5 + n) * 384;
            float d = 0.f;
#pragma unroll
            for (int j = 0; j < 6; ++j) d += u[j] * p[lane + 64 * j];
#pragma unroll
            for (int off = 1; off < 64; off <<= 1) d += __shfl_xor(d, off, 64);
            if (lane == 0) out[750 + gw * 5 + n] = 10.0f * d;
        }
    }
}

extern "C" void kernel_launch(void* const* d_in, const int* in_sizes, int n_in,
                              void* d_out, int out_size, void* d_ws, size_t ws_size,
                              hipStream_t stream) {
    const float* feat_shot  = (const float*)d_in[0];  // [2,5,5,196,384]
    const float* feat_query = (const float*)d_in[1];  // [2,75,196,384]
    const float* x_shot     = (const float*)d_in[2];  // [2,5,5,384]
    const float* x_query    = (const float*)d_in[3];  // [2,75,384]
    float* out = (float*)d_out;
    char* ws = (char*)d_ws;

    // ws layout (15.8 MiB total)
    uint8_t*  fqn   = (uint8_t*)ws;                     // 29400*384  = 11,289,600 B (fp8)
    uint8_t*  fsnp  = (uint8_t*)(ws + 11289600);        // 10240*384  =  3,932,160 B (fp8)
    float*    proto = (float*)(ws + 15221760);          //      3,840 f32
    unsigned* P     = (unsigned*)(ws + 15237120);       //    147,000 u32

    prep_kernel<<<10488, 256, 0, stream>>>(feat_query, feat_shot, x_shot,
                                           (unsigned*)fqn, (unsigned*)fsnp, proto, P);
    gemm_kernel<<<2 * 115 * 5, 256, 0, stream>>>(fqn, fsnp, P);
    final_kernel<<<226, 256, 0, stream>>>(P, x_query, proto, out);
}

// Round 7
// 198.502 us; speedup vs baseline: 1.2938x; 1.1128x over previous
//
#include <hip/hip_runtime.h>
#include <hip/hip_bf16.h>
#include <hip/hip_fp8.h>
#include <stdint.h>

// Shapes: b=2, n=5, k=5, q=75, t=196, c=384, s=k*t=980 (padded to 1024/class)
// M per b = 75*196 = 14700 (58 tiles of 256 rows). Outputs: logits[750] ++ cls_logits[750].
// Sim branch: fp8-e4m3 MX-scaled MFMA (scales=1.0); cls branch exact fp32.
// gemm: A register-resident (256 rows/block across 4 waves), B streamed ONCE per block
// through double-buffered LDS (global->VGPR->ds_write, fine-grained vmcnt hiding).
// Empirical law from rounds 4-6: dur ~= global_bytes / 7.5 TB/s -> minimize global bytes.

typedef __attribute__((ext_vector_type(8))) int int8v;      // f8f6f4 A/B operand (32 fp8)
typedef __attribute__((ext_vector_type(4))) float f32x4;    // MFMA C/D frag

__device__ __forceinline__ unsigned enc_f(float f) {
    unsigned b = __float_as_uint(f);
    return (b & 0x80000000u) ? ~b : (b | 0x80000000u);
}
__device__ __forceinline__ float dec_f(unsigned u) {
    unsigned b = (u & 0x80000000u) ? (u & 0x7FFFFFFFu) : ~u;
    return __uint_as_float(b);
}

__device__ __forceinline__ unsigned pack4_fp8(float a, float b, float c, float d) {
    int r = __builtin_amdgcn_cvt_pk_fp8_f32(a, b, 0, false);   // bytes 0,1
    r = __builtin_amdgcn_cvt_pk_fp8_f32(c, d, r, true);        // bytes 2,3
    return (unsigned)r;
}

// L2-normalize a 384-float row, emit 384 fp8 bytes (96 uint stores).
__device__ __forceinline__ void norm_row_fp8(const float* __restrict__ row,
                                             unsigned* __restrict__ o32, int lane) {
    const float4* rf4 = (const float4*)row;
    const float4 v0 = rf4[lane];
    float4 v1 = make_float4(0.f, 0.f, 0.f, 0.f);
    if (lane < 32) v1 = rf4[64 + lane];
    float ss = v0.x * v0.x + v0.y * v0.y + v0.z * v0.z + v0.w * v0.w
             + v1.x * v1.x + v1.y * v1.y + v1.z * v1.z + v1.w * v1.w;
#pragma unroll
    for (int off = 1; off < 64; off <<= 1) ss += __shfl_xor(ss, off, 64);
    const float sc = 1.0f / fmaxf(sqrtf(ss), 1e-8f);
    o32[lane] = pack4_fp8(v0.x * sc, v0.y * sc, v0.z * sc, v0.w * sc);
    if (lane < 32) o32[64 + lane] = pack4_fp8(v1.x * sc, v1.y * sc, v1.z * sc, v1.w * sc);
}

// ---------------- fused prep: norm_q | norm_s(padded) | proto | init_P ----------------
__global__ void prep_kernel(const float* __restrict__ feat_query,
                            const float* __restrict__ feat_shot,
                            const float* __restrict__ x_shot,
                            unsigned* __restrict__ fqn,
                            unsigned* __restrict__ fsnp,
                            float* __restrict__ proto,
                            unsigned* __restrict__ P) {
    const int blk  = blockIdx.x;
    const int tid  = threadIdx.x;
    const int lane = tid & 63;
    const int wv   = tid >> 6;

    if (blk < 7350) {                       // ---- query token norm -> fp8 ----
        const int gw = blk * 4 + wv;        // 0..29399
        if (gw >= 29400) return;
        norm_row_fp8(feat_query + (size_t)gw * 384, fqn + (size_t)gw * 96, lane);
    } else if (blk < 9910) {                // ---- shot token norm -> fp8 padded layout ----
        const int gw = (blk - 7350) * 4 + wv;   // 0..10239
        if (gw >= 10240) return;
        const int bn = gw >> 10;
        const int s  = gw & 1023;
        unsigned* o32 = fsnp + (size_t)gw * 96;
        if (s >= 980) {
            o32[lane] = 0u;
            if (lane < 32) o32[64 + lane] = 0u;
            return;
        }
        norm_row_fp8(feat_shot + ((size_t)bn * 980 + s) * 384, o32, lane);
    } else if (blk < 9913) {                // ---- proto = l2norm(mean_k x_shot), fp32 ----
        const int gw = (blk - 9910) * 4 + wv;
        if (gw >= 10) return;
        const float* base = x_shot + (size_t)gw * 5 * 384;
        float v[6];
        float ss = 0.f;
#pragma unroll
        for (int j = 0; j < 6; ++j) {
            float s = 0.f;
#pragma unroll
            for (int kk = 0; kk < 5; ++kk) s += base[kk * 384 + lane + 64 * j];
            s *= 0.2f;
            v[j] = s;
            ss += s * s;
        }
#pragma unroll
        for (int off = 1; off < 64; off <<= 1) ss += __shfl_xor(ss, off, 64);
        const float scale = 1.0f / fmaxf(sqrtf(ss), 1e-12f);
#pragma unroll
        for (int j = 0; j < 6; ++j) proto[(size_t)gw * 384 + lane + 64 * j] = v[j] * scale;
    } else {                                // ---- init P to encoded -inf (0) ----
        const int i = (blk - 9913) * 256 + tid;
        if (i < 147000) P[i] = 0u;
    }
}

// ---------------- fp8 GEMM + row-max: 256 A-rows in regs, B via dbuf LDS ----------------
// grid = 2b x 58mt x 5cls = 580 blocks, 256 thr = 4 waves (each holds 64 distinct rows).
// B chunk = 32 cols x 384 B = 12 KB; 32 chunks per class; double-buffered.
// LDS layout per chunk: [col][24 granules of 16B], granule slot g' holds source granule
// (g' & ~7) | ((g'&7) ^ (col&7)). Frag reads hit bank quadrant (2hi+c)^(l15&7) -> uniform.
// Staging path: global->VGPR (fine vmcnt, hidden under compute) -> ds_write after barrier.
__global__ __launch_bounds__(256, 2) void gemm_kernel(const uint8_t* __restrict__ fqn,
                                                      const uint8_t* __restrict__ fsnp,
                                                      unsigned* __restrict__ P) {
    __shared__ __align__(16) uint8_t Bl[2][12288];   // 24 KB double buffer

    const int bid = blockIdx.x;
    const int b   = bid / 290;
    const int r   = bid % 290;
    const int mt  = r / 5;
    const int cls = r % 5;
    const int m0  = mt * 256;

    const int tid  = threadIdx.x;
    const int lane = tid & 63;
    const int wv   = tid >> 6;
    const int l15  = lane & 15;
    const int hi   = lane >> 4;

    const uint8_t* Ag = fqn  + (size_t)b * 14700 * 384;
    const uint8_t* Bg = fsnp + (size_t)(b * 5 + cls) * 1024 * 384;

    // ---- A fragments -> registers (one-time; wave wv holds rows m0+wv*64 .. +63) ----
    int8v A[4][3];
#pragma unroll
    for (int mi = 0; mi < 4; ++mi) {
        int row = m0 + wv * 64 + mi * 16 + l15;
        row = row < 14700 ? row : 14699;           // clamp; dead rows masked at epilogue
        const uint8_t* pa = Ag + (size_t)row * 384 + hi * 32;
#pragma unroll
        for (int ks = 0; ks < 3; ++ks) {
            const uint4 x = *(const uint4*)(pa + ks * 128);
            const uint4 y = *(const uint4*)(pa + ks * 128 + 16);
            A[mi][ks] = (int8v){(int)x.x, (int)x.y, (int)x.z, (int)x.w,
                                (int)y.x, (int)y.y, (int)y.z, (int)y.w};
        }
    }

    // ---- staging address precompute: 3 granules of 16B per thread per chunk ----
    // LDS linear slot idx = rr*256 + tid  ->  col = idx/24, g' = idx%24;
    // source granule g = (g' & ~7) | ((g'&7) ^ (col&7)).
    int src_off[3], lds_off[3];
#pragma unroll
    for (int rr = 0; rr < 3; ++rr) {
        const int idx = rr * 256 + tid;
        const int col = idx / 24;
        const int gp  = idx - col * 24;
        const int g   = (gp & ~7) | ((gp & 7) ^ (col & 7));
        src_off[rr] = col * 384 + g * 16;
        lds_off[rr] = idx * 16;
    }

    // ---- prologue: stage chunk 0 into buffer 0 ----
#pragma unroll
    for (int rr = 0; rr < 3; ++rr) {
        const uint4 t = *(const uint4*)(Bg + src_off[rr]);
        *(uint4*)(&Bl[0][lds_off[rr]]) = t;
    }
    __syncthreads();

    float rmax[4][4];
#pragma unroll
    for (int mi = 0; mi < 4; ++mi)
#pragma unroll
        for (int i = 0; i < 4; ++i) rmax[mi][i] = -3.0e38f;

    const int c0 = ((2 * hi + 0) ^ (l15 & 7)) * 16;
    const int c1 = ((2 * hi + 1) ^ (l15 & 7)) * 16;

    for (int it = 0; it < 32; ++it) {
        // prefetch next chunk into VGPRs (vmcnt consumed only at the ds_write below)
        uint4 nx[3];
        if (it + 1 < 32) {
            const uint8_t* src = Bg + (size_t)(it + 1) * 32 * 384;
#pragma unroll
            for (int rr = 0; rr < 3; ++rr) nx[rr] = *(const uint4*)(src + src_off[rr]);
        }

        // compute on buffer it&1
        const uint8_t* buf = Bl[it & 1];
        f32x4 acc[4][2];
#pragma unroll
        for (int mi = 0; mi < 4; ++mi)
#pragma unroll
            for (int nf = 0; nf < 2; ++nf) acc[mi][nf] = (f32x4){0.f, 0.f, 0.f, 0.f};

#pragma unroll
        for (int ks = 0; ks < 3; ++ks) {
            int8v Bf[2];
#pragma unroll
            for (int nf = 0; nf < 2; ++nf) {
                const uint8_t* base = buf + (nf * 16 + l15) * 384 + ks * 128;
                const uint4 x = *(const uint4*)(base + c0);
                const uint4 y = *(const uint4*)(base + c1);
                Bf[nf] = (int8v){(int)x.x, (int)x.y, (int)x.z, (int)x.w,
                                 (int)y.x, (int)y.y, (int)y.z, (int)y.w};
            }
#pragma unroll
            for (int mi = 0; mi < 4; ++mi)
#pragma unroll
                for (int nf = 0; nf < 2; ++nf)
                    acc[mi][nf] = __builtin_amdgcn_mfma_scale_f32_16x16x128_f8f6f4(
                        A[mi][ks], Bf[nf], acc[mi][nf],
                        0, 0,                    // cbsz=fp8(e4m3), blgp=fp8(e4m3)
                        0, 0x7F7F7F7F,           // scale_a = 1.0
                        0, 0x7F7F7F7F);          // scale_b = 1.0
        }

        // fold row-max (mask padded cols >= 980)
#pragma unroll
        for (int nf = 0; nf < 2; ++nf) {
            if (it * 32 + nf * 16 + l15 < 980) {
#pragma unroll
                for (int mi = 0; mi < 4; ++mi)
#pragma unroll
                    for (int i = 0; i < 4; ++i)
                        rmax[mi][i] = fmaxf(rmax[mi][i], acc[mi][nf][i]);
            }
        }

        __syncthreads();                     // all waves done computing chunk it
        if (it + 1 < 32) {
#pragma unroll
            for (int rr = 0; rr < 3; ++rr)
                *(uint4*)(&Bl[(it + 1) & 1][lds_off[rr]]) = nx[rr];
        }
        __syncthreads();                     // writes visible before next compute
    }

    // ---- epilogue: max over the 16 col-lanes, then device-scope atomicMax ----
#pragma unroll
    for (int mi = 0; mi < 4; ++mi)
#pragma unroll
        for (int i = 0; i < 4; ++i) {
            float v = rmax[mi][i];
#pragma unroll
            for (int off = 1; off < 16; off <<= 1) v = fmaxf(v, __shfl_xor(v, off, 64));
            if (l15 == 0) {
                const int row = m0 + wv * 64 + mi * 16 + hi * 4 + i;
                if (row < 14700)
                    atomicMax(&P[(size_t)(b * 5 + cls) * 14700 + row], enc_f(v));
            }
        }
}

// ---------------- fused final: logits (mean over t of row maxima) | cls_logits ----------------
__global__ void final_kernel(const unsigned* __restrict__ P,
                             const float* __restrict__ xq,
                             const float* __restrict__ proto,
                             float* __restrict__ out) {
    const int blk  = blockIdx.x;
    const int tid  = threadIdx.x;
    const int lane = tid & 63;
    const int wv   = tid >> 6;

    if (blk < 188) {                        // ---- logits ----
        const int gw = blk * 4 + wv;        // (b*75+q)*5+n
        if (gw >= 750) return;
        const int n  = gw % 5;
        const int bq = gw / 5;
        const int b  = bq / 75;
        const int q  = bq % 75;
        const unsigned* row = P + (size_t)(b * 5 + n) * 14700 + q * 196;
        float s = 0.f;
        for (int t = lane; t < 196; t += 64) s += dec_f(row[t]);
#pragma unroll
        for (int off = 1; off < 64; off <<= 1) s += __shfl_xor(s, off, 64);
        if (lane == 0) out[gw] = s * (1.0f / 196.0f);
    } else {                                // ---- cls_logits ----
        const int gw = (blk - 188) * 4 + wv;   // b*75+q
        if (gw >= 150) return;
        const float* row = xq + (size_t)gw * 384;
        float u[6];
        float ss = 0.f;
#pragma unroll
        for (int j = 0; j < 6; ++j) { u[j] = row[lane + 64 * j]; ss += u[j] * u[j]; }
#pragma unroll
        for (int off = 1; off < 64; off <<= 1) ss += __shfl_xor(ss, off, 64);
        const float scale = 1.0f / fmaxf(sqrtf(ss), 1e-12f);
#pragma unroll
        for (int j = 0; j < 6; ++j) u[j] *= scale;
        const int b = gw / 75;
        for (int n = 0; n < 5; ++n) {
            const float* p = proto + (size_t)(b * 5 + n) * 384;
            float d = 0.f;
#pragma unroll
            for (int j = 0; j < 6; ++j) d += u[j] * p[lane + 64 * j];
#pragma unroll
            for (int off = 1; off < 64; off <<= 1) d += __shfl_xor(d, off, 64);
            if (lane == 0) out[750 + gw * 5 + n] = 10.0f * d;
        }
    }
}

extern "C" void kernel_launch(void* const* d_in, const int* in_sizes, int n_in,
                              void* d_out, int out_size, void* d_ws, size_t ws_size,
                              hipStream_t stream) {
    const float* feat_shot  = (const float*)d_in[0];  // [2,5,5,196,384]
    const float* feat_query = (const float*)d_in[1];  // [2,75,196,384]
    const float* x_shot     = (const float*)d_in[2];  // [2,5,5,384]
    const float* x_query    = (const float*)d_in[3];  // [2,75,384]
    float* out = (float*)d_out;
    char* ws = (char*)d_ws;

    // ws layout (15.8 MiB total)
    uint8_t*  fqn   = (uint8_t*)ws;                     // 29400*384  = 11,289,600 B (fp8)
    uint8_t*  fsnp  = (uint8_t*)(ws + 11289600);        // 10240*384  =  3,932,160 B (fp8)
    float*    proto = (float*)(ws + 15221760);          //      3,840 f32
    unsigned* P     = (unsigned*)(ws + 15237120);       //    147,000 u32

    prep_kernel<<<10488, 256, 0, stream>>>(feat_query, feat_shot, x_shot,
                                           (unsigned*)fqn, (unsigned*)fsnp, proto, P);
    gemm_kernel<<<2 * 58 * 5, 256, 0, stream>>>(fqn, fsnp, P);
    final_kernel<<<226, 256, 0, stream>>>(P, x_query, proto, out);
}

// Round 8
// 193.003 us; speedup vs baseline: 1.3306x; 1.0285x over previous
//
#include <hip/hip_runtime.h>
#include <hip/hip_bf16.h>
#include <hip/hip_fp8.h>
#include <stdint.h>

// Shapes: b=2, n=5, k=5, q=75, t=196, c=384, s=k*t=980 (padded to 1024/class)
// M per b = 75*196 = 14700 (58 tiles of 256 rows). Outputs: logits[750] ++ cls_logits[750].
// Sim branch: fp8-e4m3 MX-scaled MFMA (scales=1.0); cls branch exact fp32.
// gemm: A register-resident (256 rows/block, 64/wave), B streamed once per block-half
// through double-buffered LDS with ONE barrier per 64-col chunk; prefetch global->VGPR
// overlaps compute, consumed by next iteration's ds_write.
// Empirical: VMEM delivery ~7.5 TB/s aggregate (12 B/cyc/CU) -> minimize global bytes,
// then balance the grid (>=4 blocks/CU) and cut barriers.

typedef __attribute__((ext_vector_type(8))) int int8v;      // f8f6f4 A/B operand (32 fp8)
typedef __attribute__((ext_vector_type(4))) float f32x4;    // MFMA C/D frag

__device__ __forceinline__ unsigned enc_f(float f) {
    unsigned b = __float_as_uint(f);
    return (b & 0x80000000u) ? ~b : (b | 0x80000000u);
}
__device__ __forceinline__ float dec_f(unsigned u) {
    unsigned b = (u & 0x80000000u) ? (u & 0x7FFFFFFFu) : ~u;
    return __uint_as_float(b);
}

__device__ __forceinline__ unsigned pack4_fp8(float a, float b, float c, float d) {
    int r = __builtin_amdgcn_cvt_pk_fp8_f32(a, b, 0, false);   // bytes 0,1
    r = __builtin_amdgcn_cvt_pk_fp8_f32(c, d, r, true);        // bytes 2,3
    return (unsigned)r;
}

// ---------------- fused prep: norm (16 lanes/row) | proto | init_P ----------------
// blocks [0,2478): 16 rows/block (4 waves x 4 rows); rows 0..29399 = query tokens,
// rows 29400..39639 = shot tokens in padded [b*5+n][1024] layout.
// blocks [2478,2481): proto; [2481,3056): init P.
__global__ void prep_kernel(const float* __restrict__ feat_query,
                            const float* __restrict__ feat_shot,
                            const float* __restrict__ x_shot,
                            unsigned* __restrict__ fqn,
                            unsigned* __restrict__ fsnp,
                            float* __restrict__ proto,
                            unsigned* __restrict__ P) {
    const int blk  = blockIdx.x;
    const int tid  = threadIdx.x;
    const int lane = tid & 63;
    const int wv   = tid >> 6;

    if (blk < 2478) {                       // ---- token L2 norm -> fp8, 4 rows/wave ----
        const int tr  = blk * 16 + wv * 4 + (lane >> 4);   // 0..39639
        const int l16 = lane & 15;
        if (tr >= 39640) return;

        const float* row;
        unsigned* o32;
        bool zero = false;
        if (tr < 29400) {
            row = feat_query + (size_t)tr * 384;
            o32 = fqn + (size_t)tr * 96;
        } else {
            const int sp = tr - 29400;          // padded shot row: [bn][1024]
            const int bn = sp >> 10;
            const int s  = sp & 1023;
            o32 = fsnp + (size_t)sp * 96;
            row = feat_shot + ((size_t)bn * 980 + s) * 384;
            zero = (s >= 980);
        }
        if (zero) {
#pragma unroll
            for (int j = 0; j < 6; ++j) o32[l16 + 16 * j] = 0u;
            return;
        }
        const float4* rf4 = (const float4*)row;
        float4 v[6];
        float ss = 0.f;
#pragma unroll
        for (int j = 0; j < 6; ++j) {
            v[j] = rf4[l16 + 16 * j];
            ss += v[j].x * v[j].x + v[j].y * v[j].y + v[j].z * v[j].z + v[j].w * v[j].w;
        }
#pragma unroll
        for (int off = 1; off < 16; off <<= 1) ss += __shfl_xor(ss, off, 64);
        const float sc = 1.0f / fmaxf(sqrtf(ss), 1e-8f);
#pragma unroll
        for (int j = 0; j < 6; ++j)
            o32[l16 + 16 * j] = pack4_fp8(v[j].x * sc, v[j].y * sc, v[j].z * sc, v[j].w * sc);
    } else if (blk < 2481) {                // ---- proto = l2norm(mean_k x_shot), fp32 ----
        const int gw = (blk - 2478) * 4 + wv;
        if (gw >= 10) return;
        const float* base = x_shot + (size_t)gw * 5 * 384;
        float v[6];
        float ss = 0.f;
#pragma unroll
        for (int j = 0; j < 6; ++j) {
            float s = 0.f;
#pragma unroll
            for (int kk = 0; kk < 5; ++kk) s += base[kk * 384 + lane + 64 * j];
            s *= 0.2f;
            v[j] = s;
            ss += s * s;
        }
#pragma unroll
        for (int off = 1; off < 64; off <<= 1) ss += __shfl_xor(ss, off, 64);
        const float scale = 1.0f / fmaxf(sqrtf(ss), 1e-12f);
#pragma unroll
        for (int j = 0; j < 6; ++j) proto[(size_t)gw * 384 + lane + 64 * j] = v[j] * scale;
    } else {                                // ---- init P to encoded -inf (0) ----
        const int i = (blk - 2481) * 256 + tid;
        if (i < 147000) P[i] = 0u;
    }
}

// ---------------- fp8 GEMM + row-max: 256 A-rows in regs, half-class B via dbuf LDS ----------------
// grid = 2b x 5cls x 2sh x 58mt = 1160 blocks; 256 thr = 4 waves (64 rows each).
// B chunk = 64 cols x 384 B = 24 KB; 8 chunks per half-class; double-buffered (48 KB LDS).
// Loop body: ds_write cur (prefetched last iter) -> ONE barrier -> issue prefetch -> compute.
// LDS layout: [col][24 granules of 16B], slot g' holds source granule
// (g'&~7)|((g'&7)^(col&7)); frag reads hit bank quadrant (2hi+c)^(l15&7) -> uniform.
__global__ __launch_bounds__(256, 2) void gemm_kernel(const uint8_t* __restrict__ fqn,
                                                      const uint8_t* __restrict__ fsnp,
                                                      unsigned* __restrict__ P) {
    __shared__ __align__(16) uint8_t Bl[2][24576];   // 48 KB double buffer

    const int bid = blockIdx.x;       // (((b*5+cls)*2)+sh)*58 + mt
    const int mt  = bid % 58;
    const int g1  = bid / 58;
    const int sh  = g1 & 1;
    const int bc  = g1 >> 1;          // b*5+cls
    const int b   = bc / 5;
    const int m0  = mt * 256;

    const int tid  = threadIdx.x;
    const int lane = tid & 63;
    const int wv   = tid >> 6;
    const int l15  = lane & 15;
    const int hi   = lane >> 4;

    const uint8_t* Ag = fqn  + (size_t)b * 14700 * 384;
    const uint8_t* Bg = fsnp + ((size_t)bc * 1024 + sh * 512) * 384;

    // ---- A fragments -> registers (one-time; wave wv holds rows m0+wv*64 .. +63) ----
    int8v A[4][3];
#pragma unroll
    for (int mi = 0; mi < 4; ++mi) {
        int row = m0 + wv * 64 + mi * 16 + l15;
        row = row < 14700 ? row : 14699;           // clamp; dead rows masked at epilogue
        const uint8_t* pa = Ag + (size_t)row * 384 + hi * 32;
#pragma unroll
        for (int ks = 0; ks < 3; ++ks) {
            const uint4 x = *(const uint4*)(pa + ks * 128);
            const uint4 y = *(const uint4*)(pa + ks * 128 + 16);
            A[mi][ks] = (int8v){(int)x.x, (int)x.y, (int)x.z, (int)x.w,
                                (int)y.x, (int)y.y, (int)y.z, (int)y.w};
        }
    }

    // ---- staging addresses: 6 granules of 16B per thread per 64-col chunk ----
    int src_off[6], lds_off[6];
#pragma unroll
    for (int rr = 0; rr < 6; ++rr) {
        const int idx = rr * 256 + tid;            // 0..1535 slots
        const int col = idx / 24;
        const int gp  = idx - col * 24;
        const int g   = (gp & ~7) | ((gp & 7) ^ (col & 7));
        src_off[rr] = col * 384 + g * 16;
        lds_off[rr] = idx * 16;
    }

    // ---- prologue: prefetch chunk 0 into VGPRs ----
    uint4 nx[6];
#pragma unroll
    for (int rr = 0; rr < 6; ++rr) nx[rr] = *(const uint4*)(Bg + src_off[rr]);

    float rmax[4][4];
#pragma unroll
    for (int mi = 0; mi < 4; ++mi)
#pragma unroll
        for (int i = 0; i < 4; ++i) rmax[mi][i] = -3.0e38f;

    const int c0 = ((2 * hi + 0) ^ (l15 & 7)) * 16;
    const int c1 = ((2 * hi + 1) ^ (l15 & 7)) * 16;

    for (int it = 0; it < 8; ++it) {
        // write the chunk prefetched last iteration (vmcnt wait lands here, after a
        // full compute phase); buffer was last read two iterations ago (1 barrier ago).
        uint8_t* wbuf = Bl[it & 1];
#pragma unroll
        for (int rr = 0; rr < 6; ++rr) *(uint4*)(&wbuf[lds_off[rr]]) = nx[rr];
        __syncthreads();

        // issue next chunk's prefetch (overlaps the compute below)
        if (it + 1 < 8) {
            const uint8_t* src = Bg + (size_t)(it + 1) * 64 * 384;
#pragma unroll
            for (int rr = 0; rr < 6; ++rr) nx[rr] = *(const uint4*)(src + src_off[rr]);
        }

        // compute on buffer it&1
        const uint8_t* buf = Bl[it & 1];
        f32x4 acc[4][4];
#pragma unroll
        for (int mi = 0; mi < 4; ++mi)
#pragma unroll
            for (int nf = 0; nf < 4; ++nf) acc[mi][nf] = (f32x4){0.f, 0.f, 0.f, 0.f};

#pragma unroll
        for (int ks = 0; ks < 3; ++ks) {
            int8v Bf[4];
#pragma unroll
            for (int nf = 0; nf < 4; ++nf) {
                const uint8_t* base = buf + (nf * 16 + l15) * 384 + ks * 128;
                const uint4 x = *(const uint4*)(base + c0);
                const uint4 y = *(const uint4*)(base + c1);
                Bf[nf] = (int8v){(int)x.x, (int)x.y, (int)x.z, (int)x.w,
                                 (int)y.x, (int)y.y, (int)y.z, (int)y.w};
            }
#pragma unroll
            for (int mi = 0; mi < 4; ++mi)
#pragma unroll
                for (int nf = 0; nf < 4; ++nf)
                    acc[mi][nf] = __builtin_amdgcn_mfma_scale_f32_16x16x128_f8f6f4(
                        A[mi][ks], Bf[nf], acc[mi][nf],
                        0, 0,                    // cbsz=fp8(e4m3), blgp=fp8(e4m3)
                        0, 0x7F7F7F7F,           // scale_a = 1.0
                        0, 0x7F7F7F7F);          // scale_b = 1.0
        }

        // fold row-max (mask padded cols >= 980)
#pragma unroll
        for (int nf = 0; nf < 4; ++nf) {
            if (sh * 512 + it * 64 + nf * 16 + l15 < 980) {
#pragma unroll
                for (int mi = 0; mi < 4; ++mi)
#pragma unroll
                    for (int i = 0; i < 4; ++i)
                        rmax[mi][i] = fmaxf(rmax[mi][i], acc[mi][nf][i]);
            }
        }
    }

    // ---- epilogue: max over the 16 col-lanes, then device-scope atomicMax ----
#pragma unroll
    for (int mi = 0; mi < 4; ++mi)
#pragma unroll
        for (int i = 0; i < 4; ++i) {
            float v = rmax[mi][i];
#pragma unroll
            for (int off = 1; off < 16; off <<= 1) v = fmaxf(v, __shfl_xor(v, off, 64));
            if (l15 == 0) {
                const int row = m0 + wv * 64 + mi * 16 + hi * 4 + i;
                if (row < 14700)
                    atomicMax(&P[(size_t)bc * 14700 + row], enc_f(v));
            }
        }
}

// ---------------- fused final: logits (mean over t of row maxima) | cls_logits ----------------
__global__ void final_kernel(const unsigned* __restrict__ P,
                             const float* __restrict__ xq,
                             const float* __restrict__ proto,
                             float* __restrict__ out) {
    const int blk  = blockIdx.x;
    const int tid  = threadIdx.x;
    const int lane = tid & 63;
    const int wv   = tid >> 6;

    if (blk < 188) {                        // ---- logits ----
        const int gw = blk * 4 + wv;        // (b*75+q)*5+n
        if (gw >= 750) return;
        const int n  = gw % 5;
        const int bq = gw / 5;
        const int b  = bq / 75;
        const int q  = bq % 75;
        const unsigned* row = P + (size_t)(b * 5 + n) * 14700 + q * 196;
        float s = 0.f;
        for (int t = lane; t < 196; t += 64) s += dec_f(row[t]);
#pragma unroll
        for (int off = 1; off < 64; off <<= 1) s += __shfl_xor(s, off, 64);
        if (lane == 0) out[gw] = s * (1.0f / 196.0f);
    } else {                                // ---- cls_logits ----
        const int gw = (blk - 188) * 4 + wv;   // b*75+q
        if (gw >= 150) return;
        const float* row = xq + (size_t)gw * 384;
        float u[6];
        float ss = 0.f;
#pragma unroll
        for (int j = 0; j < 6; ++j) { u[j] = row[lane + 64 * j]; ss += u[j] * u[j]; }
#pragma unroll
        for (int off = 1; off < 64; off <<= 1) ss += __shfl_xor(ss, off, 64);
        const float scale = 1.0f / fmaxf(sqrtf(ss), 1e-12f);
#pragma unroll
        for (int j = 0; j < 6; ++j) u[j] *= scale;
        const int b = gw / 75;
        for (int n = 0; n < 5; ++n) {
            const float* p = proto + (size_t)(b * 5 + n) * 384;
            float d = 0.f;
#pragma unroll
            for (int j = 0; j < 6; ++j) d += u[j] * p[lane + 64 * j];
#pragma unroll
            for (int off = 1; off < 64; off <<= 1) d += __shfl_xor(d, off, 64);
            if (lane == 0) out[750 + gw * 5 + n] = 10.0f * d;
        }
    }
}

extern "C" void kernel_launch(void* const* d_in, const int* in_sizes, int n_in,
                              void* d_out, int out_size, void* d_ws, size_t ws_size,
                              hipStream_t stream) {
    const float* feat_shot  = (const float*)d_in[0];  // [2,5,5,196,384]
    const float* feat_query = (const float*)d_in[1];  // [2,75,196,384]
    const float* x_shot     = (const float*)d_in[2];  // [2,5,5,384]
    const float* x_query    = (const float*)d_in[3];  // [2,75,384]
    float* out = (float*)d_out;
    char* ws = (char*)d_ws;

    // ws layout (15.8 MiB total)
    uint8_t*  fqn   = (uint8_t*)ws;                     // 29400*384  = 11,289,600 B (fp8)
    uint8_t*  fsnp  = (uint8_t*)(ws + 11289600);        // 10240*384  =  3,932,160 B (fp8)
    float*    proto = (float*)(ws + 15221760);          //      3,840 f32
    unsigned* P     = (unsigned*)(ws + 15237120);       //    147,000 u32

    prep_kernel<<<3056, 256, 0, stream>>>(feat_query, feat_shot, x_shot,
                                          (unsigned*)fqn, (unsigned*)fsnp, proto, P);
    gemm_kernel<<<1160, 256, 0, stream>>>(fqn, fsnp, P);
    final_kernel<<<226, 256, 0, stream>>>(P, x_query, proto, out);
}

// Round 9
// 192.365 us; speedup vs baseline: 1.3350x; 1.0033x over previous
//
#include <hip/hip_runtime.h>
#include <hip/hip_bf16.h>
#include <hip/hip_fp8.h>
#include <stdint.h>

// Shapes: b=2, n=5, k=5, q=75, t=196, c=384, s=k*t=980 (padded to 1024/class)
// M per b = 75*196 = 14700 (58 tiles of 256 rows). Outputs: logits[750] ++ cls_logits[750].
// Sim branch: fp8-e4m3 MX-scaled MFMA (scales=1.0); cls branch exact fp32.
// gemm: A register-resident (256 rows/block, 64/wave), B streamed once per block-half
// through double-buffered LDS, ONE barrier per 64-col chunk; inner loop split into
// two 32-col halves (acc[4][2]) to keep unified VGPR+AGPR demand ~210 < 256
// (round-8 lesson: acc[4][4] pushed demand to ~257 -> 80 MB scratch spill traffic).

typedef __attribute__((ext_vector_type(8))) int int8v;      // f8f6f4 A/B operand (32 fp8)
typedef __attribute__((ext_vector_type(4))) float f32x4;    // MFMA C/D frag

__device__ __forceinline__ unsigned enc_f(float f) {
    unsigned b = __float_as_uint(f);
    return (b & 0x80000000u) ? ~b : (b | 0x80000000u);
}
__device__ __forceinline__ float dec_f(unsigned u) {
    unsigned b = (u & 0x80000000u) ? (u & 0x7FFFFFFFu) : ~u;
    return __uint_as_float(b);
}

__device__ __forceinline__ unsigned pack4_fp8(float a, float b, float c, float d) {
    int r = __builtin_amdgcn_cvt_pk_fp8_f32(a, b, 0, false);   // bytes 0,1
    r = __builtin_amdgcn_cvt_pk_fp8_f32(c, d, r, true);        // bytes 2,3
    return (unsigned)r;
}

// ---------------- fused prep: norm (16 lanes/row) | proto | init_P ----------------
__global__ void prep_kernel(const float* __restrict__ feat_query,
                            const float* __restrict__ feat_shot,
                            const float* __restrict__ x_shot,
                            unsigned* __restrict__ fqn,
                            unsigned* __restrict__ fsnp,
                            float* __restrict__ proto,
                            unsigned* __restrict__ P) {
    const int blk  = blockIdx.x;
    const int tid  = threadIdx.x;
    const int lane = tid & 63;
    const int wv   = tid >> 6;

    if (blk < 2478) {                       // ---- token L2 norm -> fp8, 4 rows/wave ----
        const int tr  = blk * 16 + wv * 4 + (lane >> 4);   // 0..39639
        const int l16 = lane & 15;
        if (tr >= 39640) return;

        const float* row;
        unsigned* o32;
        bool zero = false;
        if (tr < 29400) {
            row = feat_query + (size_t)tr * 384;
            o32 = fqn + (size_t)tr * 96;
        } else {
            const int sp = tr - 29400;          // padded shot row: [bn][1024]
            const int bn = sp >> 10;
            const int s  = sp & 1023;
            o32 = fsnp + (size_t)sp * 96;
            row = feat_shot + ((size_t)bn * 980 + s) * 384;
            zero = (s >= 980);
        }
        if (zero) {
#pragma unroll
            for (int j = 0; j < 6; ++j) o32[l16 + 16 * j] = 0u;
            return;
        }
        const float4* rf4 = (const float4*)row;
        float4 v[6];
        float ss = 0.f;
#pragma unroll
        for (int j = 0; j < 6; ++j) {
            v[j] = rf4[l16 + 16 * j];
            ss += v[j].x * v[j].x + v[j].y * v[j].y + v[j].z * v[j].z + v[j].w * v[j].w;
        }
#pragma unroll
        for (int off = 1; off < 16; off <<= 1) ss += __shfl_xor(ss, off, 64);
        const float sc = 1.0f / fmaxf(sqrtf(ss), 1e-8f);
#pragma unroll
        for (int j = 0; j < 6; ++j)
            o32[l16 + 16 * j] = pack4_fp8(v[j].x * sc, v[j].y * sc, v[j].z * sc, v[j].w * sc);
    } else if (blk < 2481) {                // ---- proto = l2norm(mean_k x_shot), fp32 ----
        const int gw = (blk - 2478) * 4 + wv;
        if (gw >= 10) return;
        const float* base = x_shot + (size_t)gw * 5 * 384;
        float v[6];
        float ss = 0.f;
#pragma unroll
        for (int j = 0; j < 6; ++j) {
            float s = 0.f;
#pragma unroll
            for (int kk = 0; kk < 5; ++kk) s += base[kk * 384 + lane + 64 * j];
            s *= 0.2f;
            v[j] = s;
            ss += s * s;
        }
#pragma unroll
        for (int off = 1; off < 64; off <<= 1) ss += __shfl_xor(ss, off, 64);
        const float scale = 1.0f / fmaxf(sqrtf(ss), 1e-12f);
#pragma unroll
        for (int j = 0; j < 6; ++j) proto[(size_t)gw * 384 + lane + 64 * j] = v[j] * scale;
    } else {                                // ---- init P to encoded -inf (0) ----
        const int i = (blk - 2481) * 256 + tid;
        if (i < 147000) P[i] = 0u;
    }
}

// ---------------- fp8 GEMM + row-max: 256 A-rows in regs, half-class B via dbuf LDS ----------------
// grid = 2b x 5cls x 2sh x 58mt = 1160 blocks; 256 thr = 4 waves (64 rows each).
// B chunk = 64 cols x 384 B = 24 KB; 8 chunks per half-class; double-buffered (48 KB LDS).
// Loop: ds_write cur (prefetched last iter; vmcnt lands after full compute) -> ONE barrier
// -> issue next prefetch -> compute cur in two 32-col halves (acc[4][2], no spill).
// LDS layout: [col][24 granules of 16B], slot g' holds source granule
// (g'&~7)|((g'&7)^(col&7)); frag reads hit bank quadrant (2hi+c)^(l15&7) -> uniform.
__global__ __launch_bounds__(256, 2) void gemm_kernel(const uint8_t* __restrict__ fqn,
                                                      const uint8_t* __restrict__ fsnp,
                                                      unsigned* __restrict__ P) {
    __shared__ __align__(16) uint8_t Bl[2][24576];   // 48 KB double buffer

    const int bid = blockIdx.x;       // (((b*5+cls)*2)+sh)*58 + mt
    const int mt  = bid % 58;
    const int g1  = bid / 58;
    const int sh  = g1 & 1;
    const int bc  = g1 >> 1;          // b*5+cls
    const int b   = bc / 5;
    const int m0  = mt * 256;

    const int tid  = threadIdx.x;
    const int lane = tid & 63;
    const int wv   = tid >> 6;
    const int l15  = lane & 15;
    const int hi   = lane >> 4;

    const uint8_t* Ag = fqn  + (size_t)b * 14700 * 384;
    const uint8_t* Bg = fsnp + ((size_t)bc * 1024 + sh * 512) * 384;

    // ---- A fragments -> registers (one-time; wave wv holds rows m0+wv*64 .. +63) ----
    int8v A[4][3];
#pragma unroll
    for (int mi = 0; mi < 4; ++mi) {
        int row = m0 + wv * 64 + mi * 16 + l15;
        row = row < 14700 ? row : 14699;           // clamp; dead rows masked at epilogue
        const uint8_t* pa = Ag + (size_t)row * 384 + hi * 32;
#pragma unroll
        for (int ks = 0; ks < 3; ++ks) {
            const uint4 x = *(const uint4*)(pa + ks * 128);
            const uint4 y = *(const uint4*)(pa + ks * 128 + 16);
            A[mi][ks] = (int8v){(int)x.x, (int)x.y, (int)x.z, (int)x.w,
                                (int)y.x, (int)y.y, (int)y.z, (int)y.w};
        }
    }

    // ---- staging addresses: 6 granules of 16B per thread per 64-col chunk ----
    int src_off[6], lds_off[6];
#pragma unroll
    for (int rr = 0; rr < 6; ++rr) {
        const int idx = rr * 256 + tid;            // 0..1535 slots
        const int col = idx / 24;
        const int gp  = idx - col * 24;
        const int g   = (gp & ~7) | ((gp & 7) ^ (col & 7));
        src_off[rr] = col * 384 + g * 16;
        lds_off[rr] = idx * 16;
    }

    // ---- prologue: prefetch chunk 0 into VGPRs ----
    uint4 nx[6];
#pragma unroll
    for (int rr = 0; rr < 6; ++rr) nx[rr] = *(const uint4*)(Bg + src_off[rr]);

    float rmax[4][4];
#pragma unroll
    for (int mi = 0; mi < 4; ++mi)
#pragma unroll
        for (int i = 0; i < 4; ++i) rmax[mi][i] = -3.0e38f;

    const int c0 = ((2 * hi + 0) ^ (l15 & 7)) * 16;
    const int c1 = ((2 * hi + 1) ^ (l15 & 7)) * 16;

    for (int it = 0; it < 8; ++it) {
        // write the chunk prefetched last iteration (vmcnt wait lands here, after a
        // full compute phase); buffer was last read one barrier ago.
        uint8_t* wbuf = Bl[it & 1];
#pragma unroll
        for (int rr = 0; rr < 6; ++rr) *(uint4*)(&wbuf[lds_off[rr]]) = nx[rr];
        __syncthreads();

        // issue next chunk's prefetch (overlaps the compute below)
        if (it + 1 < 8) {
            const uint8_t* src = Bg + (size_t)(it + 1) * 64 * 384;
#pragma unroll
            for (int rr = 0; rr < 6; ++rr) nx[rr] = *(const uint4*)(src + src_off[rr]);
        }

        // compute on buffer it&1, two 32-col halves to bound register demand
        const uint8_t* buf = Bl[it & 1];
#pragma unroll
        for (int np = 0; np < 2; ++np) {
            f32x4 acc[4][2];
#pragma unroll
            for (int mi = 0; mi < 4; ++mi)
#pragma unroll
                for (int nf = 0; nf < 2; ++nf) acc[mi][nf] = (f32x4){0.f, 0.f, 0.f, 0.f};

#pragma unroll
            for (int ks = 0; ks < 3; ++ks) {
                int8v Bf[2];
#pragma unroll
                for (int nf = 0; nf < 2; ++nf) {
                    const uint8_t* base = buf + ((np * 2 + nf) * 16 + l15) * 384 + ks * 128;
                    const uint4 x = *(const uint4*)(base + c0);
                    const uint4 y = *(const uint4*)(base + c1);
                    Bf[nf] = (int8v){(int)x.x, (int)x.y, (int)x.z, (int)x.w,
                                     (int)y.x, (int)y.y, (int)y.z, (int)y.w};
                }
#pragma unroll
                for (int mi = 0; mi < 4; ++mi)
#pragma unroll
                    for (int nf = 0; nf < 2; ++nf)
                        acc[mi][nf] = __builtin_amdgcn_mfma_scale_f32_16x16x128_f8f6f4(
                            A[mi][ks], Bf[nf], acc[mi][nf],
                            0, 0,                    // cbsz=fp8(e4m3), blgp=fp8(e4m3)
                            0, 0x7F7F7F7F,           // scale_a = 1.0
                            0, 0x7F7F7F7F);          // scale_b = 1.0
            }

            // fold row-max (mask padded cols >= 980)
#pragma unroll
            for (int nf = 0; nf < 2; ++nf) {
                if (sh * 512 + it * 64 + (np * 2 + nf) * 16 + l15 < 980) {
#pragma unroll
                    for (int mi = 0; mi < 4; ++mi)
#pragma unroll
                        for (int i = 0; i < 4; ++i)
                            rmax[mi][i] = fmaxf(rmax[mi][i], acc[mi][nf][i]);
                }
            }
        }
    }

    // ---- epilogue: max over the 16 col-lanes, then device-scope atomicMax ----
#pragma unroll
    for (int mi = 0; mi < 4; ++mi)
#pragma unroll
        for (int i = 0; i < 4; ++i) {
            float v = rmax[mi][i];
#pragma unroll
            for (int off = 1; off < 16; off <<= 1) v = fmaxf(v, __shfl_xor(v, off, 64));
            if (l15 == 0) {
                const int row = m0 + wv * 64 + mi * 16 + hi * 4 + i;
                if (row < 14700)
                    atomicMax(&P[(size_t)bc * 14700 + row], enc_f(v));
            }
        }
}

// ---------------- fused final: logits (mean over t of row maxima) | cls_logits ----------------
__global__ void final_kernel(const unsigned* __restrict__ P,
                             const float* __restrict__ xq,
                             const float* __restrict__ proto,
                             float* __restrict__ out) {
    const int blk  = blockIdx.x;
    const int tid  = threadIdx.x;
    const int lane = tid & 63;
    const int wv   = tid >> 6;

    if (blk < 188) {                        // ---- logits ----
        const int gw = blk * 4 + wv;        // (b*75+q)*5+n
        if (gw >= 750) return;
        const int n  = gw % 5;
        const int bq = gw / 5;
        const int b  = bq / 75;
        const int q  = bq % 75;
        const unsigned* row = P + (size_t)(b * 5 + n) * 14700 + q * 196;
        float s = 0.f;
        for (int t = lane; t < 196; t += 64) s += dec_f(row[t]);
#pragma unroll
        for (int off = 1; off < 64; off <<= 1) s += __shfl_xor(s, off, 64);
        if (lane == 0) out[gw] = s * (1.0f / 196.0f);
    } else {                                // ---- cls_logits ----
        const int gw = (blk - 188) * 4 + wv;   // b*75+q
        if (gw >= 150) return;
        const float* row = xq + (size_t)gw * 384;
        float u[6];
        float ss = 0.f;
#pragma unroll
        for (int j = 0; j < 6; ++j) { u[j] = row[lane + 64 * j]; ss += u[j] * u[j]; }
#pragma unroll
        for (int off = 1; off < 64; off <<= 1) ss += __shfl_xor(ss, off, 64);
        const float scale = 1.0f / fmaxf(sqrtf(ss), 1e-12f);
#pragma unroll
        for (int j = 0; j < 6; ++j) u[j] *= scale;
        const int b = gw / 75;
        for (int n = 0; n < 5; ++n) {
            const float* p = proto + (size_t)(b * 5 + n) * 384;
            float d = 0.f;
#pragma unroll
            for (int j = 0; j < 6; ++j) d += u[j] * p[lane + 64 * j];
#pragma unroll
            for (int off = 1; off < 64; off <<= 1) d += __shfl_xor(d, off, 64);
            if (lane == 0) out[750 + gw * 5 + n] = 10.0f * d;
        }
    }
}

extern "C" void kernel_launch(void* const* d_in, const int* in_sizes, int n_in,
                              void* d_out, int out_size, void* d_ws, size_t ws_size,
                              hipStream_t stream) {
    const float* feat_shot  = (const float*)d_in[0];  // [2,5,5,196,384]
    const float* feat_query = (const float*)d_in[1];  // [2,75,196,384]
    const float* x_shot     = (const float*)d_in[2];  // [2,5,5,384]
    const float* x_query    = (const float*)d_in[3];  // [2,75,384]
    float* out = (float*)d_out;
    char* ws = (char*)d_ws;

    // ws layout (15.8 MiB total)
    uint8_t*  fqn   = (uint8_t*)ws;                     // 29400*384  = 11,289,600 B (fp8)
    uint8_t*  fsnp  = (uint8_t*)(ws + 11289600);        // 10240*384  =  3,932,160 B (fp8)
    float*    proto = (float*)(ws + 15221760);          //      3,840 f32
    unsigned* P     = (unsigned*)(ws + 15237120);       //    147,000 u32

    prep_kernel<<<3056, 256, 0, stream>>>(feat_query, feat_shot, x_shot,
                                          (unsigned*)fqn, (unsigned*)fsnp, proto, P);
    gemm_kernel<<<1160, 256, 0, stream>>>(fqn, fsnp, P);
    final_kernel<<<226, 256, 0, stream>>>(P, x_query, proto, out);
}

// Round 10
// 157.686 us; speedup vs baseline: 1.6286x; 1.2199x over previous
//
#include <hip/hip_runtime.h>
#include <hip/hip_bf16.h>
#include <hip/hip_fp8.h>
#include <stdint.h>

// Shapes: b=2, n=5, k=5, q=75, t=196, c=384, s=k*t=980 (padded to 1024/class)
// M per b = 75*196 = 14700 (58 tiles of 256 rows). Outputs: logits[750] ++ cls_logits[750].
// Sim branch: fp8-e4m3 MX-scaled MFMA (scales=1.0); cls branch exact fp32.
// gemm: A register-resident (256 rows/block, 64/wave), B streamed once per block-half
// through double-buffered LDS, ONE barrier per 32-col chunk.
// Register discipline (round-8/9 lesson): 64-col chunks (nx[6] + wide addressing) push
// the allocator past its 128-VGPR split -> ~80 MB scratch spill traffic on the 7.5 TB/s
// VMEM path. Round-7's 32-col inner loop compiles to 104 VGPR with no spill -> keep it.

typedef __attribute__((ext_vector_type(8))) int int8v;      // f8f6f4 A/B operand (32 fp8)
typedef __attribute__((ext_vector_type(4))) float f32x4;    // MFMA C/D frag

__device__ __forceinline__ unsigned enc_f(float f) {
    unsigned b = __float_as_uint(f);
    return (b & 0x80000000u) ? ~b : (b | 0x80000000u);
}
__device__ __forceinline__ float dec_f(unsigned u) {
    unsigned b = (u & 0x80000000u) ? (u & 0x7FFFFFFFu) : ~u;
    return __uint_as_float(b);
}

__device__ __forceinline__ unsigned pack4_fp8(float a, float b, float c, float d) {
    int r = __builtin_amdgcn_cvt_pk_fp8_f32(a, b, 0, false);   // bytes 0,1
    r = __builtin_amdgcn_cvt_pk_fp8_f32(c, d, r, true);        // bytes 2,3
    return (unsigned)r;
}

// ---------------- fused prep: norm (16 lanes/row) | proto | init_P ----------------
__global__ void prep_kernel(const float* __restrict__ feat_query,
                            const float* __restrict__ feat_shot,
                            const float* __restrict__ x_shot,
                            unsigned* __restrict__ fqn,
                            unsigned* __restrict__ fsnp,
                            float* __restrict__ proto,
                            unsigned* __restrict__ P) {
    const int blk  = blockIdx.x;
    const int tid  = threadIdx.x;
    const int lane = tid & 63;
    const int wv   = tid >> 6;

    if (blk < 2478) {                       // ---- token L2 norm -> fp8, 4 rows/wave ----
        const int tr  = blk * 16 + wv * 4 + (lane >> 4);   // 0..39639
        const int l16 = lane & 15;
        if (tr >= 39640) return;

        const float* row;
        unsigned* o32;
        bool zero = false;
        if (tr < 29400) {
            row = feat_query + (size_t)tr * 384;
            o32 = fqn + (size_t)tr * 96;
        } else {
            const int sp = tr - 29400;          // padded shot row: [bn][1024]
            const int bn = sp >> 10;
            const int s  = sp & 1023;
            o32 = fsnp + (size_t)sp * 96;
            row = feat_shot + ((size_t)bn * 980 + s) * 384;
            zero = (s >= 980);
        }
        if (zero) {
#pragma unroll
            for (int j = 0; j < 6; ++j) o32[l16 + 16 * j] = 0u;
            return;
        }
        const float4* rf4 = (const float4*)row;
        float4 v[6];
        float ss = 0.f;
#pragma unroll
        for (int j = 0; j < 6; ++j) {
            v[j] = rf4[l16 + 16 * j];
            ss += v[j].x * v[j].x + v[j].y * v[j].y + v[j].z * v[j].z + v[j].w * v[j].w;
        }
#pragma unroll
        for (int off = 1; off < 16; off <<= 1) ss += __shfl_xor(ss, off, 64);
        const float sc = 1.0f / fmaxf(sqrtf(ss), 1e-8f);
#pragma unroll
        for (int j = 0; j < 6; ++j)
            o32[l16 + 16 * j] = pack4_fp8(v[j].x * sc, v[j].y * sc, v[j].z * sc, v[j].w * sc);
    } else if (blk < 2481) {                // ---- proto = l2norm(mean_k x_shot), fp32 ----
        const int gw = (blk - 2478) * 4 + wv;
        if (gw >= 10) return;
        const float* base = x_shot + (size_t)gw * 5 * 384;
        float v[6];
        float ss = 0.f;
#pragma unroll
        for (int j = 0; j < 6; ++j) {
            float s = 0.f;
#pragma unroll
            for (int kk = 0; kk < 5; ++kk) s += base[kk * 384 + lane + 64 * j];
            s *= 0.2f;
            v[j] = s;
            ss += s * s;
        }
#pragma unroll
        for (int off = 1; off < 64; off <<= 1) ss += __shfl_xor(ss, off, 64);
        const float scale = 1.0f / fmaxf(sqrtf(ss), 1e-12f);
#pragma unroll
        for (int j = 0; j < 6; ++j) proto[(size_t)gw * 384 + lane + 64 * j] = v[j] * scale;
    } else {                                // ---- init P to encoded -inf (0) ----
        const int i = (blk - 2481) * 256 + tid;
        if (i < 147000) P[i] = 0u;
    }
}

// ---------------- fp8 GEMM + row-max: 256 A-rows in regs, half-class B via dbuf LDS ----------------
// grid = 2b x 5cls x 2sh x 58mt = 1160 blocks; 256 thr = 4 waves (64 rows each).
// B chunk = 32 cols x 384 B = 12 KB; 16 chunks per half-class; double-buffered (24 KB LDS).
// Loop: ds_write cur (prefetched last iter; vmcnt lands after a full compute phase)
// -> ONE barrier -> issue next prefetch -> compute (3 ks x [2 B-frags, 8 MFMA]).
// Safety of the single barrier: reads of a buffer and the next write to it are separated
// by exactly one barrier (write it uses buf[it&1], last read at compute it-2, and
// barrier(it-1) sits between; the concurrent compute it-1 reads the OTHER buffer).
// LDS layout: [col][24 granules of 16B], slot g' holds source granule
// (g'&~7)|((g'&7)^(col&7)); frag reads hit bank quadrant (2hi+c)^(l15&7) -> uniform.
__global__ __launch_bounds__(256, 2) void gemm_kernel(const uint8_t* __restrict__ fqn,
                                                      const uint8_t* __restrict__ fsnp,
                                                      unsigned* __restrict__ P) {
    __shared__ __align__(16) uint8_t Bl[2][12288];   // 24 KB double buffer

    const int bid = blockIdx.x;       // (((b*5+cls)*2)+sh)*58 + mt
    const int mt  = bid % 58;
    const int g1  = bid / 58;
    const int sh  = g1 & 1;
    const int bc  = g1 >> 1;          // b*5+cls
    const int b   = bc / 5;
    const int m0  = mt * 256;

    const int tid  = threadIdx.x;
    const int lane = tid & 63;
    const int wv   = tid >> 6;
    const int l15  = lane & 15;
    const int hi   = lane >> 4;

    const uint8_t* Ag = fqn  + (size_t)b * 14700 * 384;
    const uint8_t* Bg = fsnp + ((size_t)bc * 1024 + sh * 512) * 384;

    // ---- A fragments -> registers (one-time; wave wv holds rows m0+wv*64 .. +63) ----
    int8v A[4][3];
#pragma unroll
    for (int mi = 0; mi < 4; ++mi) {
        int row = m0 + wv * 64 + mi * 16 + l15;
        row = row < 14700 ? row : 14699;           // clamp; dead rows masked at epilogue
        const uint8_t* pa = Ag + (size_t)row * 384 + hi * 32;
#pragma unroll
        for (int ks = 0; ks < 3; ++ks) {
            const uint4 x = *(const uint4*)(pa + ks * 128);
            const uint4 y = *(const uint4*)(pa + ks * 128 + 16);
            A[mi][ks] = (int8v){(int)x.x, (int)x.y, (int)x.z, (int)x.w,
                                (int)y.x, (int)y.y, (int)y.z, (int)y.w};
        }
    }

    // ---- staging addresses: 3 granules of 16B per thread per 32-col chunk ----
    int src_off[3];
#pragma unroll
    for (int rr = 0; rr < 3; ++rr) {
        const int idx = rr * 256 + tid;            // 0..767 slots
        const int col = idx / 24;
        const int gp  = idx - col * 24;
        const int g   = (gp & ~7) | ((gp & 7) ^ (col & 7));
        src_off[rr] = col * 384 + g * 16;
    }
    const int lds_base = tid * 16;                 // + rr*4096 immediate

    // ---- prologue: prefetch chunk 0 into VGPRs ----
    uint4 nx0 = *(const uint4*)(Bg + src_off[0]);
    uint4 nx1 = *(const uint4*)(Bg + src_off[1]);
    uint4 nx2 = *(const uint4*)(Bg + src_off[2]);

    float rmax[4][4];
#pragma unroll
    for (int mi = 0; mi < 4; ++mi)
#pragma unroll
        for (int i = 0; i < 4; ++i) rmax[mi][i] = -3.0e38f;

    const int c0 = ((2 * hi + 0) ^ (l15 & 7)) * 16;
    const int c1 = ((2 * hi + 1) ^ (l15 & 7)) * 16;

    for (int it = 0; it < 16; ++it) {
        // write the chunk prefetched last iteration (vmcnt wait lands here, after a
        // full compute phase)
        uint8_t* wbuf = Bl[it & 1];
        *(uint4*)(&wbuf[lds_base])        = nx0;
        *(uint4*)(&wbuf[lds_base + 4096]) = nx1;
        *(uint4*)(&wbuf[lds_base + 8192]) = nx2;
        __syncthreads();

        // issue next chunk's prefetch (overlaps the compute below)
        if (it + 1 < 16) {
            const uint8_t* src = Bg + (size_t)(it + 1) * 32 * 384;
            nx0 = *(const uint4*)(src + src_off[0]);
            nx1 = *(const uint4*)(src + src_off[1]);
            nx2 = *(const uint4*)(src + src_off[2]);
        }

        // compute on buffer it&1
        const uint8_t* buf = Bl[it & 1];
        f32x4 acc[4][2];
#pragma unroll
        for (int mi = 0; mi < 4; ++mi)
#pragma unroll
            for (int nf = 0; nf < 2; ++nf) acc[mi][nf] = (f32x4){0.f, 0.f, 0.f, 0.f};

#pragma unroll
        for (int ks = 0; ks < 3; ++ks) {
            int8v Bf[2];
#pragma unroll
            for (int nf = 0; nf < 2; ++nf) {
                const uint8_t* base = buf + (nf * 16 + l15) * 384 + ks * 128;
                const uint4 x = *(const uint4*)(base + c0);
                const uint4 y = *(const uint4*)(base + c1);
                Bf[nf] = (int8v){(int)x.x, (int)x.y, (int)x.z, (int)x.w,
                                 (int)y.x, (int)y.y, (int)y.z, (int)y.w};
            }
#pragma unroll
            for (int mi = 0; mi < 4; ++mi)
#pragma unroll
                for (int nf = 0; nf < 2; ++nf)
                    acc[mi][nf] = __builtin_amdgcn_mfma_scale_f32_16x16x128_f8f6f4(
                        A[mi][ks], Bf[nf], acc[mi][nf],
                        0, 0,                    // cbsz=fp8(e4m3), blgp=fp8(e4m3)
                        0, 0x7F7F7F7F,           // scale_a = 1.0
                        0, 0x7F7F7F7F);          // scale_b = 1.0
        }

        // fold row-max (mask padded cols >= 980)
#pragma unroll
        for (int nf = 0; nf < 2; ++nf) {
            if (sh * 512 + it * 32 + nf * 16 + l15 < 980) {
#pragma unroll
                for (int mi = 0; mi < 4; ++mi)
#pragma unroll
                    for (int i = 0; i < 4; ++i)
                        rmax[mi][i] = fmaxf(rmax[mi][i], acc[mi][nf][i]);
            }
        }
    }

    // ---- epilogue: max over the 16 col-lanes, then device-scope atomicMax ----
#pragma unroll
    for (int mi = 0; mi < 4; ++mi)
#pragma unroll
        for (int i = 0; i < 4; ++i) {
            float v = rmax[mi][i];
#pragma unroll
            for (int off = 1; off < 16; off <<= 1) v = fmaxf(v, __shfl_xor(v, off, 64));
            if (l15 == 0) {
                const int row = m0 + wv * 64 + mi * 16 + hi * 4 + i;
                if (row < 14700)
                    atomicMax(&P[(size_t)bc * 14700 + row], enc_f(v));
            }
        }
}

// ---------------- fused final: logits (mean over t of row maxima) | cls_logits ----------------
__global__ void final_kernel(const unsigned* __restrict__ P,
                             const float* __restrict__ xq,
                             const float* __restrict__ proto,
                             float* __restrict__ out) {
    const int blk  = blockIdx.x;
    const int tid  = threadIdx.x;
    const int lane = tid & 63;
    const int wv   = tid >> 6;

    if (blk < 188) {                        // ---- logits ----
        const int gw = blk * 4 + wv;        // (b*75+q)*5+n
        if (gw >= 750) return;
        const int n  = gw % 5;
        const int bq = gw / 5;
        const int b  = bq / 75;
        const int q  = bq % 75;
        const unsigned* row = P + (size_t)(b * 5 + n) * 14700 + q * 196;
        float s = 0.f;
        for (int t = lane; t < 196; t += 64) s += dec_f(row[t]);
#pragma unroll
        for (int off = 1; off < 64; off <<= 1) s += __shfl_xor(s, off, 64);
        if (lane == 0) out[gw] = s * (1.0f / 196.0f);
    } else {                                // ---- cls_logits ----
        const int gw = (blk - 188) * 4 + wv;   // b*75+q
        if (gw >= 150) return;
        const float* row = xq + (size_t)gw * 384;
        float u[6];
        float ss = 0.f;
#pragma unroll
        for (int j = 0; j < 6; ++j) { u[j] = row[lane + 64 * j]; ss += u[j] * u[j]; }
#pragma unroll
        for (int off = 1; off < 64; off <<= 1) ss += __shfl_xor(ss, off, 64);
        const float scale = 1.0f / fmaxf(sqrtf(ss), 1e-12f);
#pragma unroll
        for (int j = 0; j < 6; ++j) u[j] *= scale;
        const int b = gw / 75;
        for (int n = 0; n < 5; ++n) {
            const float* p = proto + (size_t)(b * 5 + n) * 384;
            float d = 0.f;
#pragma unroll
            for (int j = 0; j < 6; ++j) d += u[j] * p[lane + 64 * j];
#pragma unroll
            for (int off = 1; off < 64; off <<= 1) d += __shfl_xor(d, off, 64);
            if (lane == 0) out[750 + gw * 5 + n] = 10.0f * d;
        }
    }
}

extern "C" void kernel_launch(void* const* d_in, const int* in_sizes, int n_in,
                              void* d_out, int out_size, void* d_ws, size_t ws_size,
                              hipStream_t stream) {
    const float* feat_shot  = (const float*)d_in[0];  // [2,5,5,196,384]
    const float* feat_query = (const float*)d_in[1];  // [2,75,196,384]
    const float* x_shot     = (const float*)d_in[2];  // [2,5,5,384]
    const float* x_query    = (const float*)d_in[3];  // [2,75,384]
    float* out = (float*)d_out;
    char* ws = (char*)d_ws;

    // ws layout (15.8 MiB total)
    uint8_t*  fqn   = (uint8_t*)ws;                     // 29400*384  = 11,289,600 B (fp8)
    uint8_t*  fsnp  = (uint8_t*)(ws + 11289600);        // 10240*384  =  3,932,160 B (fp8)
    float*    proto = (float*)(ws + 15221760);          //      3,840 f32
    unsigned* P     = (unsigned*)(ws + 15237120);       //    147,000 u32

    prep_kernel<<<3056, 256, 0, stream>>>(feat_query, feat_shot, x_shot,
                                          (unsigned*)fqn, (unsigned*)fsnp, proto, P);
    gemm_kernel<<<1160, 256, 0, stream>>>(fqn, fsnp, P);
    final_kernel<<<226, 256, 0, stream>>>(P, x_query, proto, out);
}